// Round 14
// baseline (215.841 us; speedup 1.0000x reference)
//
#include <hip/hip_runtime.h>

typedef __attribute__((ext_vector_type(8))) short s16x8;   // 8 bf16
typedef __attribute__((ext_vector_type(4))) float f32x4;
typedef __attribute__((ext_vector_type(4))) int   i32x4;

#define HID 512
#define NROWS 8192
#define TAU_INV 1.25f
#define LOG2E 1.4426950408889634f

// counted waits + raw barrier (T3/T4). memory clobber: LDS/VMEM may not cross.
#define VMCNT(n)  asm volatile("s_waitcnt vmcnt(" #n ")" ::: "memory")
#define LGKMCNT0  asm volatile("s_waitcnt lgkmcnt(0)" ::: "memory")
#define BARRIER   asm volatile("s_barrier" ::: "memory")

__device__ __forceinline__ float bf2f(short s) {
    union { unsigned u; float f; } v;
    v.u = ((unsigned)(unsigned short)s) << 16;
    return v.f;
}
__device__ __forceinline__ short f2bf(float f) {
    unsigned u = __float_as_uint(f);
    u += 0x7fffu + ((u >> 16) & 1u);   // round-to-nearest-even
    return (short)(u >> 16);
}

__device__ __forceinline__ void gload_lds16(const void* g, void* l) {
    __builtin_amdgcn_global_load_lds(
        (const __attribute__((address_space(1))) unsigned int*)g,
        (__attribute__((address_space(3))) unsigned int*)l, 16, 0, 0);
}

__device__ __forceinline__ int dot4i(int a, int b) {
    int s = 0;
#pragma unroll
    for (int i = 0; i < 4; ++i)
        s += (int)(signed char)(a >> (8 * i)) * (int)(signed char)(b >> (8 * i));
    return s;
}

// ---------------------------------------------------------------------------
// Fused fp32->bf16 convert for z_mp, z_sc, W1, W2 + zeroing of rowsum/colsum
// (tail blocks), all in one launch.  (R1-verified)
// ---------------------------------------------------------------------------
__global__ void convert_all(const float* __restrict__ z1, const float* __restrict__ z2,
                            const float* __restrict__ w1, const float* __restrict__ w2,
                            short* __restrict__ Zb1, short* __restrict__ Zb2,
                            short* __restrict__ Wb1, short* __restrict__ Wb2,
                            float* __restrict__ zsum)
{
    const int ZN = NROWS * HID, WN = HID * HID;
    const int NCONV = (2 * ZN + 2 * WN) / 1024;   // conversion blocks
    if ((int)blockIdx.x >= NCONV) {               // tail: zero rowsum+colsum
        int zi = ((int)blockIdx.x - NCONV) * 1024 + threadIdx.x * 4;
        if (zi < 2 * NROWS)
            *(float4*)(zsum + zi) = make_float4(0.f, 0.f, 0.f, 0.f);
        return;
    }
    long i = (long)(blockIdx.x * blockDim.x + threadIdx.x) * 4;
    const float* src;
    short* dst;
    long off;
    if (i < ZN)                { src = z1; dst = Zb1; off = i; }
    else if (i < 2L * ZN)      { src = z2; dst = Zb2; off = i - ZN; }
    else if (i < 2L * ZN + WN) { src = w1; dst = Wb1; off = i - 2L * ZN; }
    else                       { src = w2; dst = Wb2; off = i - 2L * ZN - WN; }
    float4 v = *(const float4*)(src + off);
    short4 o;
    o.x = f2bf(v.x); o.y = f2bf(v.y); o.z = f2bf(v.z); o.w = f2bf(v.w);
    *(short4*)(dst + off) = o;
}

// ---------------------------------------------------------------------------
// bf16 NT GEMM — RETILED 64x64 (was 64x128) to unblock the occupancy lever:
// grid (128,8,2) = 2048 blocks -> 8/CU available; LDS 16 KB/block; acc
// shrinks to 16 regs -> ~60 VGPR; __launch_bounds__(256,6) caps VGPR ~85
// (no spill, R4 lesson) -> 6 blocks/CU = 24 waves (was 16). Schedule =
// R12/R13-proven 2-buffer EARLY-ISSUE phase-pair pipeline: stage(kt+1)
// before the counted wait; VMCNT(2) retires kt's 2 FIFO-oldest loads,
// kt+1 stays in flight across the barrier. WAR: buf (kt+1)&1 was last
// ds_read in kt-1; reads < own lgkmcnt(0) < kt-1 closing barrier < kt top.
// 4 waves of 32x32 (2x2 mfma_f32_16x16x32_bf16); B (=W, 512 KB) is
// L2-resident so the extra B-refetch across M-blocks is HBM-free.
// ---------------------------------------------------------------------------
__global__ __launch_bounds__(256, 6)
void gemm_proj(const short* __restrict__ A0, const short* __restrict__ A1,
               const short* __restrict__ B, const float* __restrict__ bias,
               short* __restrict__ C0, short* __restrict__ C1, int do_elu)
{
    __shared__ short ldsA[2][64 * 32];    // 2 x 4 KB
    __shared__ short ldsB[2][64 * 32];    // 2 x 4 KB
    const short* A = blockIdx.z ? A1 : A0;
    short* C = blockIdx.z ? C1 : C0;
    const int tid = threadIdx.x;
    const int w = tid >> 6, lane = tid & 63;
    const int wm = w & 1, wn = w >> 1;    // 2x2 waves of 32x32
    const int quad = lane >> 4, r16 = lane & 15;
    const int bM = blockIdx.x * 64, bN = blockIdx.y * 64;
    const int lrow = lane >> 2;
    const int lq   = ((lane & 3) ^ ((lane >> 3) & 3)) * 8;   // swizzled src slot (shorts)
    const int aswz = (quad ^ ((r16 >> 1) & 3)) * 8;          // swizzled read slot (shorts)

    auto stage = [&](int kt, int sb) {    // 2 gload_lds per wave (1 A + 1 B)
        const int k0 = kt * 32;
        const int r0 = w * 16;            // each wave stages 16 rows of A and B
        gload_lds16(A + (size_t)(bM + r0 + lrow) * HID + k0 + lq, &ldsA[sb][r0 * 32]);
        gload_lds16(B + (size_t)(bN + r0 + lrow) * HID + k0 + lq, &ldsB[sb][r0 * 32]);
    };

    f32x4 acc[2][2] = {};

    stage(0, 0);                          // kt=0 in flight

    const int NT = HID / 32;              // 16 K-tiles
#pragma unroll
    for (int kt = 0; kt < NT; ++kt) {
        const int rb = kt & 1, sb = rb ^ 1;
        if (kt < NT - 1) {
            stage(kt + 1, sb);            // EARLY-ISSUE before the wait
            VMCNT(2);                     // kt resident; kt+1 in flight
        } else {
            VMCNT(0);
        }
        BARRIER;
        s16x8 af[2], bfr[2];
#pragma unroll
        for (int t = 0; t < 2; ++t) {
            af[t]  = *(const s16x8*)&ldsA[rb][(wm * 32 + t * 16 + r16) * 32 + aswz];
            bfr[t] = *(const s16x8*)&ldsB[rb][(wn * 32 + t * 16 + r16) * 32 + aswz];
        }
        BARRIER; LGKMCNT0;
        __builtin_amdgcn_s_setprio(1);
#pragma unroll
        for (int tm = 0; tm < 2; ++tm)
#pragma unroll
            for (int tn = 0; tn < 2; ++tn)
                acc[tm][tn] = __builtin_amdgcn_mfma_f32_16x16x32_bf16(
                    af[tm], bfr[tn], acc[tm][tn], 0, 0, 0);
        __builtin_amdgcn_s_setprio(0);
        BARRIER;
    }

#pragma unroll
    for (int tn = 0; tn < 2; ++tn) {
        int gcol = bN + wn * 32 + tn * 16 + r16;
        float bv = bias[gcol];
#pragma unroll
        for (int tm = 0; tm < 2; ++tm) {
#pragma unroll
            for (int r = 0; r < 4; ++r) {
                int grow = bM + wm * 32 + tm * 16 + quad * 4 + r;  // C/D: row=(lane>>4)*4+reg
                float v = acc[tm][tn][r] + bv;
                if (do_elu) v = v > 0.f ? v : __expf(v) - 1.f;
                C[(size_t)grow * HID + gcol] = f2bf(v);
            }
        }
    }
}

// ---------------------------------------------------------------------------
// normalize + int8 row-quantize: q = round(n * 127/max|n_row|), one wave/row.
// recip[row] = max|n_row|/127, so dot_real = i32acc * recip[r] * recip[c].
// ---------------------------------------------------------------------------
__global__ void normalize_quant(const short* __restrict__ P, char* __restrict__ Q,
                                float* __restrict__ recip, int nrows)
{
    int gt = blockIdx.x * blockDim.x + threadIdx.x;
    int row = gt >> 6, lane = gt & 63;
    if (row >= nrows) return;
    const short* p = P + (size_t)row * HID + lane * 8;
    s16x8 v = *(const s16x8*)p;
    float f[8], ss = 0.f, am = 0.f;
#pragma unroll
    for (int i = 0; i < 8; ++i) {
        f[i] = bf2f(v[i]);
        ss += f[i] * f[i];
        am = fmaxf(am, fabsf(f[i]));
    }
#pragma unroll
    for (int m = 1; m < 64; m <<= 1) {
        ss += __shfl_xor(ss, m, 64);
        am = fmaxf(am, __shfl_xor(am, m, 64));
    }
    float inv = rsqrtf(ss);
    float maxn = am * inv;             // max |n_i| over the row
    float s = 127.f / maxn;
    int lo = 0, hi = 0;
#pragma unroll
    for (int i = 0; i < 4; ++i) {
        int q0 = (int)lrintf(f[i] * inv * s);
        int q1 = (int)lrintf(f[i + 4] * inv * s);
        lo |= (q0 & 255) << (8 * i);
        hi |= (q1 & 255) << (8 * i);
    }
    ((int2*)(Q + (size_t)row * HID))[lane] = make_int2(lo, hi);
    if (lane == 0) recip[row] = maxn * (1.f / 127.f);
}

// ---------------------------------------------------------------------------
// int8 similarity — R12-verified best (71.1 us): 128x128 tile, 2-buffer
// early-issue phase-pair pipeline, 4 blocks/CU, LDS-first reduction.
// Untouched.
// ---------------------------------------------------------------------------
__global__ __launch_bounds__(256, 4)
void gemm_sim(const char* __restrict__ Q1, const char* __restrict__ Q2,
              const float* __restrict__ recip,
              float* __restrict__ rowsum, float* __restrict__ colsum)
{
    __shared__ char  ldsA[2][128 * 64];   // 2 x 8 KB
    __shared__ char  ldsB[2][128 * 64];   // 2 x 8 KB
    __shared__ float red[256];            // 128 row + 128 col partials
    const int tid = threadIdx.x;
    const int w = tid >> 6, lane = tid & 63;
    const int wm = w >> 1, wn = w & 1;
    const int quad = lane >> 4, r16 = lane & 15;
    const int bM = blockIdx.x * 128, bN = blockIdx.y * 128;
    const int lrow = lane >> 2;
    const int lq   = ((lane & 3) ^ ((lane >> 3) & 3)) * 16;  // swizzled src slot (bytes)
    const int aswz = (quad ^ ((r16 >> 1) & 3)) * 16;         // swizzled read slot (bytes)

    auto stage = [&](int kt, int sb) {   // 4 gload_lds per wave (2 A + 2 B)
        const int k0 = kt * 64;
#pragma unroll
        for (int i = 0; i < 2; ++i) {
            int r0 = (w * 2 + i) * 16;
            gload_lds16(Q1 + (size_t)(bM + r0 + lrow) * HID + k0 + lq, &ldsA[sb][r0 * 64]);
            gload_lds16(Q2 + (size_t)(bN + r0 + lrow) * HID + k0 + lq, &ldsB[sb][r0 * 64]);
        }
    };

    i32x4 acc[4][4] = {};

    stage(0, 0);                          // kt=0 in flight

    const int NT = HID / 64;              // 8 K-tiles
#pragma unroll
    for (int kt = 0; kt < NT; ++kt) {
        const int rb = kt & 1, sb = rb ^ 1;
        if (kt < NT - 1) {
            stage(kt + 1, sb);            // EARLY-ISSUE before the wait
            VMCNT(4);                     // kt resident; kt+1 in flight
        } else {
            VMCNT(0);
        }
        BARRIER;
        i32x4 af[4], bfr[4];
#pragma unroll
        for (int t = 0; t < 4; ++t) {
            af[t]  = *(const i32x4*)&ldsA[rb][(wm * 64 + t * 16 + r16) * 64 + aswz];
            bfr[t] = *(const i32x4*)&ldsB[rb][(wn * 64 + t * 16 + r16) * 64 + aswz];
        }
        BARRIER; LGKMCNT0;
        __builtin_amdgcn_s_setprio(1);
#pragma unroll
        for (int tm = 0; tm < 4; ++tm)
#pragma unroll
            for (int tn = 0; tn < 4; ++tn)
                acc[tm][tn] = __builtin_amdgcn_mfma_i32_16x16x64_i8(
                    af[tm], bfr[tn], acc[tm][tn], 0, 0, 0);
        __builtin_amdgcn_s_setprio(0);
        BARRIER;
    }

    // ---- epilogue: LDS-first reduction, then 1 global atomic per element ----
    red[tid] = 0.f;
    __syncthreads();

    float cb[4], cs[4] = {0.f, 0.f, 0.f, 0.f};
#pragma unroll
    for (int tn = 0; tn < 4; ++tn)
        cb[tn] = recip[NROWS + bN + wn * 64 + tn * 16 + r16] * (TAU_INV * LOG2E);

#pragma unroll
    for (int tm = 0; tm < 4; ++tm) {
#pragma unroll
        for (int r = 0; r < 4; ++r) {
            int lr = wm * 64 + tm * 16 + quad * 4 + r;         // C/D: row=quad*4+reg
            float ra = recip[bM + lr];
            float rs = 0.f;
#pragma unroll
            for (int tn = 0; tn < 4; ++tn) {
                float e = exp2f((float)acc[tm][tn][r] * ra * cb[tn]);
                rs += e;
                cs[tn] += e;
            }
#pragma unroll
            for (int m = 1; m < 16; m <<= 1) rs += __shfl_xor(rs, m, 64);
            if (r16 == 0) atomicAdd(&red[lr], rs);             // LDS atomic
        }
    }
#pragma unroll
    for (int tn = 0; tn < 4; ++tn) {
        float c = cs[tn];
        c += __shfl_xor(c, 16, 64);
        c += __shfl_xor(c, 32, 64);
        if (quad == 0)
            atomicAdd(&red[128 + wn * 64 + tn * 16 + r16], c); // LDS atomic
    }
    __syncthreads();
    if (tid < 128) atomicAdd(&rowsum[bM + tid], red[tid]);
    else           atomicAdd(&colsum[bN + tid - 128], red[tid]);
}

// ---------------------------------------------------------------------------
// Edge numerators, one wave per node (edges are row-sorted, 8 per node):
// row fragments loaded once; exact int8 dots in float; direct store (no atomic).
// ---------------------------------------------------------------------------
__global__ void edge_kernel(const char* __restrict__ Q1, const char* __restrict__ Q2,
                            const float* __restrict__ recip, const int* __restrict__ pos,
                            float* __restrict__ smp, float* __restrict__ ssc, int E)
{
    int row = blockIdx.x * (blockDim.x >> 6) + (threadIdx.x >> 6);
    int lane = threadIdx.x & 63;
    if (row >= NROWS) return;
    int2 a1 = ((const int2*)(Q1 + (size_t)row * HID))[lane];
    int2 a2 = ((const int2*)(Q2 + (size_t)row * HID))[lane];
    float s1 = 0.f, s2 = 0.f;
    float ir1 = recip[row], ir2 = recip[NROWS + row];
#pragma unroll
    for (int e = 0; e < 8; ++e) {
        int c = pos[E + row * 8 + e];
        int2 b2 = ((const int2*)(Q2 + (size_t)c * HID))[lane];
        int2 b1 = ((const int2*)(Q1 + (size_t)c * HID))[lane];
        float d1 = (float)(dot4i(a1.x, b2.x) + dot4i(a1.y, b2.y));
        float d2 = (float)(dot4i(b1.x, a2.x) + dot4i(b1.y, a2.y));
#pragma unroll
        for (int m = 1; m < 64; m <<= 1) {
            d1 += __shfl_xor(d1, m, 64);
            d2 += __shfl_xor(d2, m, 64);
        }
        if (lane == 0) {
            s1 += __expf(d1 * ir1 * recip[NROWS + c] * TAU_INV);   // S[row,c]
            s2 += __expf(d2 * recip[c] * ir2 * TAU_INV);           // S[c,row]
        }
    }
    if (lane == 0) { smp[row] = s1; ssc[row] = s2; }
}

// Single-block finalize (1024 threads): loss = mean over rows -> out[0].
__global__ void finalize(const float* __restrict__ rowsum, const float* __restrict__ colsum,
                         const float* __restrict__ smp, const float* __restrict__ ssc,
                         float* __restrict__ out, int n)
{
    float contrib = 0.f;
    for (int i = threadIdx.x; i < n; i += blockDim.x) {
        float t = (smp[i] / rowsum[i]) * (ssc[i] / colsum[i]);
        contrib += -0.5f * logf(t) / (float)n;
    }
#pragma unroll
    for (int m = 1; m < 64; m <<= 1) contrib += __shfl_xor(contrib, m, 64);
    __shared__ float wsum[16];
    int w = threadIdx.x >> 6, lane = threadIdx.x & 63;
    if (lane == 0) wsum[w] = contrib;
    __syncthreads();
    if (threadIdx.x == 0) {
        float s = 0.f;
#pragma unroll
        for (int i = 0; i < 16; ++i) s += wsum[i];
        out[0] = s;
    }
}

extern "C" void kernel_launch(void* const* d_in, const int* in_sizes, int n_in,
                              void* d_out, int out_size, void* d_ws, size_t ws_size,
                              hipStream_t stream)
{
    const float* z_mp = (const float*)d_in[0];
    const float* z_sc = (const float*)d_in[1];
    const float* W1f  = (const float*)d_in[2];
    const float* b1   = (const float*)d_in[3];
    const float* W2f  = (const float*)d_in[4];
    const float* b2   = (const float*)d_in[5];
    const int*   pos  = (const int*)d_in[6];
    const int E = in_sizes[6] / 2;
    const int ZN = NROWS * HID;       // 4M elems
    const int WN = HID * HID;         // 256K elems

    // workspace layout (~34 MB):
    //   [0,16MB)   : Zb_mp, Zb_sc (bf16) -> dead after proj1 -> reused as P1,P2
    //   [16,32MB)  : H1,H2 (bf16) -> dead after proj2 -> reused as Q (int8, 8MB)
    //   [32MB,..)  : Wb1, Wb2, rowsum, colsum, recip(64KB), smp, ssc
    char* ws = (char*)d_ws;
    short* Zb1 = (short*)ws;
    short* Zb2 = Zb1 + ZN;
    short* P1  = Zb1;                 // alias: Zb dead after proj1
    short* P2  = Zb2;
    short* H1  = (short*)(ws + (size_t)16 * 1024 * 1024);
    short* H2  = H1 + ZN;
    char*  Q   = (char*)H1;           // alias: H dead after proj2; 2*NROWS rows
    char*  Q1  = Q;
    char*  Q2  = Q + (size_t)NROWS * HID;
    short* Wb1 = (short*)(ws + (size_t)32 * 1024 * 1024);
    short* Wb2 = Wb1 + WN;
    float* rowsum = (float*)(Wb2 + WN);
    float* colsum = rowsum + NROWS;
    float* recip  = colsum + NROWS;   // 2*NROWS floats
    float* smp    = recip + 2 * NROWS;
    float* ssc    = smp + NROWS;

    dim3 blk(256);
    // fp32 -> bf16 conversions + rowsum/colsum zeroing (single launch)
    convert_all<<<dim3((2 * ZN + 2 * WN) / 1024 + 16), blk, 0, stream>>>(
        z_mp, z_sc, W1f, W2f, Zb1, Zb2, Wb1, Wb2, rowsum);
    // H = elu(Z @ W1^T + b1) for both inputs (grid.z); 64x64 tiles, 6 blocks/CU
    gemm_proj<<<dim3(128, 8, 2), blk, 0, stream>>>(Zb1, Zb2, Wb1, b1, H1, H2, 1);
    // P = H @ W2^T + b2   (P overwrites Zb region — Zb dead now)
    gemm_proj<<<dim3(128, 8, 2), blk, 0, stream>>>(H1, H2, Wb2, b2, P1, P2, 0);
    // normalize + int8 quantize both P1,P2 (2*NROWS contiguous rows) -> Q, recip
    normalize_quant<<<dim3((2 * NROWS) / 4), blk, 0, stream>>>(P1, Q, recip, 2 * NROWS);
    // rowsum/colsum via i8 MFMA, 128x128 tiles, 2-buf early-issue pipeline, 4 blocks/CU
    gemm_sim<<<dim3(64, 64), blk, 0, stream>>>(Q1, Q2, recip, rowsum, colsum);
    // per-edge numerators, one wave per node, direct store
    edge_kernel<<<dim3(NROWS / 4), blk, 0, stream>>>(Q1, Q2, recip, pos, smp, ssc, E);
    // single-block reduce straight into d_out
    finalize<<<dim3(1), dim3(1024), 0, stream>>>(rowsum, colsum, smp, ssc, (float*)d_out, NROWS);
}

// Round 15
// 208.214 us; speedup vs baseline: 1.0366x; 1.0366x over previous
//
#include <hip/hip_runtime.h>

typedef __attribute__((ext_vector_type(8))) short s16x8;   // 8 bf16
typedef __attribute__((ext_vector_type(4))) float f32x4;
typedef __attribute__((ext_vector_type(4))) int   i32x4;

#define HID 512
#define NROWS 8192
#define TAU_INV 1.25f
#define LOG2E 1.4426950408889634f

// counted waits + raw barrier (T3/T4). memory clobber: LDS/VMEM may not cross.
#define VMCNT(n)  asm volatile("s_waitcnt vmcnt(" #n ")" ::: "memory")
#define LGKMCNT0  asm volatile("s_waitcnt lgkmcnt(0)" ::: "memory")
#define BARRIER   asm volatile("s_barrier" ::: "memory")

__device__ __forceinline__ float bf2f(short s) {
    union { unsigned u; float f; } v;
    v.u = ((unsigned)(unsigned short)s) << 16;
    return v.f;
}
__device__ __forceinline__ short f2bf(float f) {
    unsigned u = __float_as_uint(f);
    u += 0x7fffu + ((u >> 16) & 1u);   // round-to-nearest-even
    return (short)(u >> 16);
}

__device__ __forceinline__ void gload_lds16(const void* g, void* l) {
    __builtin_amdgcn_global_load_lds(
        (const __attribute__((address_space(1))) unsigned int*)g,
        (__attribute__((address_space(3))) unsigned int*)l, 16, 0, 0);
}

// ---------------------------------------------------------------------------
// Fused fp32->bf16 convert for z_mp, z_sc, W1, W2 + zeroing of rowsum/colsum
// (tail blocks), all in one launch.  (R1-verified)
// ---------------------------------------------------------------------------
__global__ void convert_all(const float* __restrict__ z1, const float* __restrict__ z2,
                            const float* __restrict__ w1, const float* __restrict__ w2,
                            short* __restrict__ Zb1, short* __restrict__ Zb2,
                            short* __restrict__ Wb1, short* __restrict__ Wb2,
                            float* __restrict__ zsum)
{
    const int ZN = NROWS * HID, WN = HID * HID;
    const int NCONV = (2 * ZN + 2 * WN) / 1024;   // conversion blocks
    if ((int)blockIdx.x >= NCONV) {               // tail: zero rowsum+colsum
        int zi = ((int)blockIdx.x - NCONV) * 1024 + threadIdx.x * 4;
        if (zi < 2 * NROWS)
            *(float4*)(zsum + zi) = make_float4(0.f, 0.f, 0.f, 0.f);
        return;
    }
    long i = (long)(blockIdx.x * blockDim.x + threadIdx.x) * 4;
    const float* src;
    short* dst;
    long off;
    if (i < ZN)                { src = z1; dst = Zb1; off = i; }
    else if (i < 2L * ZN)      { src = z2; dst = Zb2; off = i - ZN; }
    else if (i < 2L * ZN + WN) { src = w1; dst = Wb1; off = i - 2L * ZN; }
    else                       { src = w2; dst = Wb2; off = i - 2L * ZN - WN; }
    float4 v = *(const float4*)(src + off);
    short4 o;
    o.x = f2bf(v.x); o.y = f2bf(v.y); o.z = f2bf(v.z); o.w = f2bf(v.w);
    *(short4*)(dst + off) = o;
}

// ---------------------------------------------------------------------------
// bf16 NT GEMM, 64x128 tile — R13-measured best (209.0 us total): 2-buffer
// EARLY-ISSUE phase-pair pipeline (stage(kt+1) before the counted wait;
// VMCNT(3) retires kt's 3 FIFO-oldest loads, kt+1 stays in flight across
// the barrier). R14 falsified the 64x64 occupancy retile (-7 us: halved
// MFMA-per-barrier-pair, overhead fraction rose) — reverted exactly here.
// WAR: buf (kt+1)&1 was last ds_read in kt-1; reads < own lgkmcnt(0) <
// kt-1 closing barrier < kt top. LDS 24 KB; (256,5) cap ~102, usage ~80.
// ---------------------------------------------------------------------------
__global__ __launch_bounds__(256, 5)
void gemm_proj(const short* __restrict__ A0, const short* __restrict__ A1,
               const short* __restrict__ B, const float* __restrict__ bias,
               short* __restrict__ C0, short* __restrict__ C1, int do_elu)
{
    __shared__ short ldsA[2][64 * 32];    // 2 x 4 KB
    __shared__ short ldsB[2][128 * 32];   // 2 x 8 KB
    const short* A = blockIdx.z ? A1 : A0;
    short* C = blockIdx.z ? C1 : C0;
    const int tid = threadIdx.x;
    const int w = tid >> 6, lane = tid & 63;
    const int wm = w & 1, wn = w >> 1;
    const int quad = lane >> 4, r16 = lane & 15;
    const int bM = blockIdx.x * 64, bN = blockIdx.y * 128;
    const int lrow = lane >> 2;
    const int lq   = ((lane & 3) ^ ((lane >> 3) & 3)) * 8;   // swizzled src slot (shorts)
    const int aswz = (quad ^ ((r16 >> 1) & 3)) * 8;          // swizzled read slot (shorts)

    auto stage = [&](int kt, int sb) {    // 3 gload_lds per wave (1 A + 2 B)
        const int k0 = kt * 32;
        {   int r0 = w * 16;
            gload_lds16(A + (size_t)(bM + r0 + lrow) * HID + k0 + lq, &ldsA[sb][r0 * 32]);
        }
#pragma unroll
        for (int i = 0; i < 2; ++i) {
            int r0 = (w * 2 + i) * 16;
            gload_lds16(B + (size_t)(bN + r0 + lrow) * HID + k0 + lq, &ldsB[sb][r0 * 32]);
        }
    };

    f32x4 acc[2][4] = {};

    stage(0, 0);                          // kt=0 in flight

    const int NT = HID / 32;              // 16 K-tiles
#pragma unroll
    for (int kt = 0; kt < NT; ++kt) {
        const int rb = kt & 1, sb = rb ^ 1;
        if (kt < NT - 1) {
            stage(kt + 1, sb);            // EARLY-ISSUE before the wait
            VMCNT(3);                     // kt resident; kt+1 in flight
        } else {
            VMCNT(0);
        }
        BARRIER;
        s16x8 af[2], bfr[4];
#pragma unroll
        for (int t = 0; t < 2; ++t)
            af[t]  = *(const s16x8*)&ldsA[rb][(wm * 32 + t * 16 + r16) * 32 + aswz];
#pragma unroll
        for (int t = 0; t < 4; ++t)
            bfr[t] = *(const s16x8*)&ldsB[rb][(wn * 64 + t * 16 + r16) * 32 + aswz];
        BARRIER; LGKMCNT0;
        __builtin_amdgcn_s_setprio(1);
#pragma unroll
        for (int tm = 0; tm < 2; ++tm)
#pragma unroll
            for (int tn = 0; tn < 4; ++tn)
                acc[tm][tn] = __builtin_amdgcn_mfma_f32_16x16x32_bf16(
                    af[tm], bfr[tn], acc[tm][tn], 0, 0, 0);
        __builtin_amdgcn_s_setprio(0);
        BARRIER;
    }

#pragma unroll
    for (int tn = 0; tn < 4; ++tn) {
        int gcol = bN + wn * 64 + tn * 16 + r16;
        float bv = bias[gcol];
#pragma unroll
        for (int tm = 0; tm < 2; ++tm) {
#pragma unroll
            for (int r = 0; r < 4; ++r) {
                int grow = bM + wm * 32 + tm * 16 + quad * 4 + r;  // C/D: row=(lane>>4)*4+reg
                float v = acc[tm][tn][r] + bv;
                if (do_elu) v = v > 0.f ? v : __expf(v) - 1.f;
                C[(size_t)grow * HID + gcol] = f2bf(v);
            }
        }
    }
}

// ---------------------------------------------------------------------------
// normalize + int8 row-quantize: q = round(n * 127/max|n_row|), one wave/row.
// recip[row] = max|n_row|/127, so dot_real = i32acc * recip[r] * recip[c].
// ---------------------------------------------------------------------------
__global__ void normalize_quant(const short* __restrict__ P, char* __restrict__ Q,
                                float* __restrict__ recip, int nrows)
{
    int gt = blockIdx.x * blockDim.x + threadIdx.x;
    int row = gt >> 6, lane = gt & 63;
    if (row >= nrows) return;
    const short* p = P + (size_t)row * HID + lane * 8;
    s16x8 v = *(const s16x8*)p;
    float f[8], ss = 0.f, am = 0.f;
#pragma unroll
    for (int i = 0; i < 8; ++i) {
        f[i] = bf2f(v[i]);
        ss += f[i] * f[i];
        am = fmaxf(am, fabsf(f[i]));
    }
#pragma unroll
    for (int m = 1; m < 64; m <<= 1) {
        ss += __shfl_xor(ss, m, 64);
        am = fmaxf(am, __shfl_xor(am, m, 64));
    }
    float inv = rsqrtf(ss);
    float maxn = am * inv;             // max |n_i| over the row
    float s = 127.f / maxn;
    int lo = 0, hi = 0;
#pragma unroll
    for (int i = 0; i < 4; ++i) {
        int q0 = (int)lrintf(f[i] * inv * s);
        int q1 = (int)lrintf(f[i + 4] * inv * s);
        lo |= (q0 & 255) << (8 * i);
        hi |= (q1 & 255) << (8 * i);
    }
    ((int2*)(Q + (size_t)row * HID))[lane] = make_int2(lo, hi);
    if (lane == 0) recip[row] = maxn * (1.f / 127.f);
}

// ---------------------------------------------------------------------------
// int8 similarity — R12-verified best (71.1 us): 128x128 tile, 2-buffer
// early-issue phase-pair pipeline, 4 blocks/CU, LDS-first reduction.
// Untouched.
// ---------------------------------------------------------------------------
__global__ __launch_bounds__(256, 4)
void gemm_sim(const char* __restrict__ Q1, const char* __restrict__ Q2,
              const float* __restrict__ recip,
              float* __restrict__ rowsum, float* __restrict__ colsum)
{
    __shared__ char  ldsA[2][128 * 64];   // 2 x 8 KB
    __shared__ char  ldsB[2][128 * 64];   // 2 x 8 KB
    __shared__ float red[256];            // 128 row + 128 col partials
    const int tid = threadIdx.x;
    const int w = tid >> 6, lane = tid & 63;
    const int wm = w >> 1, wn = w & 1;
    const int quad = lane >> 4, r16 = lane & 15;
    const int bM = blockIdx.x * 128, bN = blockIdx.y * 128;
    const int lrow = lane >> 2;
    const int lq   = ((lane & 3) ^ ((lane >> 3) & 3)) * 16;  // swizzled src slot (bytes)
    const int aswz = (quad ^ ((r16 >> 1) & 3)) * 16;         // swizzled read slot (bytes)

    auto stage = [&](int kt, int sb) {   // 4 gload_lds per wave (2 A + 2 B)
        const int k0 = kt * 64;
#pragma unroll
        for (int i = 0; i < 2; ++i) {
            int r0 = (w * 2 + i) * 16;
            gload_lds16(Q1 + (size_t)(bM + r0 + lrow) * HID + k0 + lq, &ldsA[sb][r0 * 64]);
            gload_lds16(Q2 + (size_t)(bN + r0 + lrow) * HID + k0 + lq, &ldsB[sb][r0 * 64]);
        }
    };

    i32x4 acc[4][4] = {};

    stage(0, 0);                          // kt=0 in flight

    const int NT = HID / 64;              // 8 K-tiles
#pragma unroll
    for (int kt = 0; kt < NT; ++kt) {
        const int rb = kt & 1, sb = rb ^ 1;
        if (kt < NT - 1) {
            stage(kt + 1, sb);            // EARLY-ISSUE before the wait
            VMCNT(4);                     // kt resident; kt+1 in flight
        } else {
            VMCNT(0);
        }
        BARRIER;
        i32x4 af[4], bfr[4];
#pragma unroll
        for (int t = 0; t < 4; ++t) {
            af[t]  = *(const i32x4*)&ldsA[rb][(wm * 64 + t * 16 + r16) * 64 + aswz];
            bfr[t] = *(const i32x4*)&ldsB[rb][(wn * 64 + t * 16 + r16) * 64 + aswz];
        }
        BARRIER; LGKMCNT0;
        __builtin_amdgcn_s_setprio(1);
#pragma unroll
        for (int tm = 0; tm < 4; ++tm)
#pragma unroll
            for (int tn = 0; tn < 4; ++tn)
                acc[tm][tn] = __builtin_amdgcn_mfma_i32_16x16x64_i8(
                    af[tm], bfr[tn], acc[tm][tn], 0, 0, 0);
        __builtin_amdgcn_s_setprio(0);
        BARRIER;
    }

    // ---- epilogue: LDS-first reduction, then 1 global atomic per element ----
    red[tid] = 0.f;
    __syncthreads();

    float cb[4], cs[4] = {0.f, 0.f, 0.f, 0.f};
#pragma unroll
    for (int tn = 0; tn < 4; ++tn)
        cb[tn] = recip[NROWS + bN + wn * 64 + tn * 16 + r16] * (TAU_INV * LOG2E);

#pragma unroll
    for (int tm = 0; tm < 4; ++tm) {
#pragma unroll
        for (int r = 0; r < 4; ++r) {
            int lr = wm * 64 + tm * 16 + quad * 4 + r;         // C/D: row=quad*4+reg
            float ra = recip[bM + lr];
            float rs = 0.f;
#pragma unroll
            for (int tn = 0; tn < 4; ++tn) {
                float e = exp2f((float)acc[tm][tn][r] * ra * cb[tn]);
                rs += e;
                cs[tn] += e;
            }
#pragma unroll
            for (int m = 1; m < 16; m <<= 1) rs += __shfl_xor(rs, m, 64);
            if (r16 == 0) atomicAdd(&red[lr], rs);             // LDS atomic
        }
    }
#pragma unroll
    for (int tn = 0; tn < 4; ++tn) {
        float c = cs[tn];
        c += __shfl_xor(c, 16, 64);
        c += __shfl_xor(c, 32, 64);
        if (quad == 0)
            atomicAdd(&red[128 + wn * 64 + tn * 16 + r16], c); // LDS atomic
    }
    __syncthreads();
    if (tid < 128) atomicAdd(&rowsum[bM + tid], red[tid]);
    else           atomicAdd(&colsum[bN + tid - 128], red[tid]);
}

// ---------------------------------------------------------------------------
// Edge numerators, one wave per node (edges are row-sorted, 8 per node):
// row fragments loaded once; int8 dots via HW v_dot4_i32_i8 (sdot4: 1 instr
// vs 16 VALU for the hand-rolled byte-extract version); exp2 fold.
// ---------------------------------------------------------------------------
__global__ void edge_kernel(const char* __restrict__ Q1, const char* __restrict__ Q2,
                            const float* __restrict__ recip, const int* __restrict__ pos,
                            float* __restrict__ smp, float* __restrict__ ssc, int E)
{
    int row = blockIdx.x * (blockDim.x >> 6) + (threadIdx.x >> 6);
    int lane = threadIdx.x & 63;
    if (row >= NROWS) return;
    int2 a1 = ((const int2*)(Q1 + (size_t)row * HID))[lane];
    int2 a2 = ((const int2*)(Q2 + (size_t)row * HID))[lane];
    float s1 = 0.f, s2 = 0.f;
    float ir1 = recip[row] * (TAU_INV * LOG2E), ir2 = recip[NROWS + row] * (TAU_INV * LOG2E);
#pragma unroll
    for (int e = 0; e < 8; ++e) {
        int c = pos[E + row * 8 + e];
        int2 b2 = ((const int2*)(Q2 + (size_t)c * HID))[lane];
        int2 b1 = ((const int2*)(Q1 + (size_t)c * HID))[lane];
        float d1 = (float)__builtin_amdgcn_sdot4(a1.y, b2.y,
                          __builtin_amdgcn_sdot4(a1.x, b2.x, 0, false), false);
        float d2 = (float)__builtin_amdgcn_sdot4(b1.y, a2.y,
                          __builtin_amdgcn_sdot4(b1.x, a2.x, 0, false), false);
#pragma unroll
        for (int m = 1; m < 64; m <<= 1) {
            d1 += __shfl_xor(d1, m, 64);
            d2 += __shfl_xor(d2, m, 64);
        }
        if (lane == 0) {
            s1 += exp2f(d1 * ir1 * recip[NROWS + c]);   // S[row,c]
            s2 += exp2f(d2 * recip[c] * ir2);           // S[c,row]
        }
    }
    if (lane == 0) { smp[row] = s1; ssc[row] = s2; }
}

// Single-block finalize (1024 threads): loss = mean over rows -> out[0].
__global__ void finalize(const float* __restrict__ rowsum, const float* __restrict__ colsum,
                         const float* __restrict__ smp, const float* __restrict__ ssc,
                         float* __restrict__ out, int n)
{
    float contrib = 0.f;
    for (int i = threadIdx.x; i < n; i += blockDim.x) {
        float t = (smp[i] / rowsum[i]) * (ssc[i] / colsum[i]);
        contrib += -0.5f * logf(t) / (float)n;
    }
#pragma unroll
    for (int m = 1; m < 64; m <<= 1) contrib += __shfl_xor(contrib, m, 64);
    __shared__ float wsum[16];
    int w = threadIdx.x >> 6, lane = threadIdx.x & 63;
    if (lane == 0) wsum[w] = contrib;
    __syncthreads();
    if (threadIdx.x == 0) {
        float s = 0.f;
#pragma unroll
        for (int i = 0; i < 16; ++i) s += wsum[i];
        out[0] = s;
    }
}

extern "C" void kernel_launch(void* const* d_in, const int* in_sizes, int n_in,
                              void* d_out, int out_size, void* d_ws, size_t ws_size,
                              hipStream_t stream)
{
    const float* z_mp = (const float*)d_in[0];
    const float* z_sc = (const float*)d_in[1];
    const float* W1f  = (const float*)d_in[2];
    const float* b1   = (const float*)d_in[3];
    const float* W2f  = (const float*)d_in[4];
    const float* b2   = (const float*)d_in[5];
    const int*   pos  = (const int*)d_in[6];
    const int E = in_sizes[6] / 2;
    const int ZN = NROWS * HID;       // 4M elems
    const int WN = HID * HID;         // 256K elems

    // workspace layout (~34 MB):
    //   [0,16MB)   : Zb_mp, Zb_sc (bf16) -> dead after proj1 -> reused as P1,P2
    //   [16,32MB)  : H1,H2 (bf16) -> dead after proj2 -> reused as Q (int8, 8MB)
    //   [32MB,..)  : Wb1, Wb2, rowsum, colsum, recip(64KB), smp, ssc
    char* ws = (char*)d_ws;
    short* Zb1 = (short*)ws;
    short* Zb2 = Zb1 + ZN;
    short* P1  = Zb1;                 // alias: Zb dead after proj1
    short* P2  = Zb2;
    short* H1  = (short*)(ws + (size_t)16 * 1024 * 1024);
    short* H2  = H1 + ZN;
    char*  Q   = (char*)H1;           // alias: H dead after proj2; 2*NROWS rows
    char*  Q1  = Q;
    char*  Q2  = Q + (size_t)NROWS * HID;
    short* Wb1 = (short*)(ws + (size_t)32 * 1024 * 1024);
    short* Wb2 = Wb1 + WN;
    float* rowsum = (float*)(Wb2 + WN);
    float* colsum = rowsum + NROWS;
    float* recip  = colsum + NROWS;   // 2*NROWS floats
    float* smp    = recip + 2 * NROWS;
    float* ssc    = smp + NROWS;

    dim3 blk(256);
    // fp32 -> bf16 conversions + rowsum/colsum zeroing (single launch)
    convert_all<<<dim3((2 * ZN + 2 * WN) / 1024 + 16), blk, 0, stream>>>(
        z_mp, z_sc, W1f, W2f, Zb1, Zb2, Wb1, Wb2, rowsum);
    // H = elu(Z @ W1^T + b1) for both inputs (grid.z); R13 config (measured best)
    gemm_proj<<<dim3(128, 4, 2), blk, 0, stream>>>(Zb1, Zb2, Wb1, b1, H1, H2, 1);
    // P = H @ W2^T + b2   (P overwrites Zb region — Zb dead now)
    gemm_proj<<<dim3(128, 4, 2), blk, 0, stream>>>(H1, H2, Wb2, b2, P1, P2, 0);
    // normalize + int8 quantize both P1,P2 (2*NROWS contiguous rows) -> Q, recip
    normalize_quant<<<dim3((2 * NROWS) / 4), blk, 0, stream>>>(P1, Q, recip, 2 * NROWS);
    // rowsum/colsum via i8 MFMA, 128x128 tiles, 2-buf early-issue pipeline, 4 blocks/CU
    gemm_sim<<<dim3(64, 64), blk, 0, stream>>>(Q1, Q2, recip, rowsum, colsum);
    // per-edge numerators, one wave per node, sdot4 + direct store
    edge_kernel<<<dim3(NROWS / 4), blk, 0, stream>>>(Q1, Q2, recip, pos, smp, ssc, E);
    // single-block reduce straight into d_out
    finalize<<<dim3(1), dim3(1024), 0, stream>>>(rowsum, colsum, smp, ssc, (float*)d_out, NROWS);
}